// Round 3
// baseline (114.581 us; speedup 1.0000x reference)
//
#include <hip/hip_runtime.h>
#include <math.h>

#define NN 4096
#define NV4 1024            // NN/4 float4s per row
#define RPW 4               // rows per wave
#define ROWS_PER_BLOCK 16   // 4 waves x 4 rows
#define BLK 256

// ---------- small helpers ----------

__device__ __forceinline__ float4 ld4(const float* __restrict__ p, int t) {
    return reinterpret_cast<const float4*>(p)[t];
}
__device__ __forceinline__ void st4(float* __restrict__ p, int t, float4 v) {
    reinterpret_cast<float4*>(p)[t] = v;
}
__device__ __forceinline__ float4 add4(float4 a, float4 b) {
    return make_float4(a.x + b.x, a.y + b.y, a.z + b.z, a.w + b.w);
}

// block-wide (sum, sumsq) reduction, blockDim.x == 1024 (16 waves)
__device__ __forceinline__ float2 block_reduce2(float s, float ss, float* sbuf) {
    #pragma unroll
    for (int off = 32; off > 0; off >>= 1) {
        s  += __shfl_down(s,  off, 64);
        ss += __shfl_down(ss, off, 64);
    }
    const int wave = threadIdx.x >> 6;
    const int lane = threadIdx.x & 63;
    if (lane == 0) { sbuf[wave] = s; sbuf[16 + wave] = ss; }
    __syncthreads();
    float rs = 0.f, rss = 0.f;
    if (threadIdx.x < 16) { rs = sbuf[threadIdx.x]; rss = sbuf[16 + threadIdx.x]; }
    if (wave == 0) {
        #pragma unroll
        for (int off = 8; off > 0; off >>= 1) {
            rs  += __shfl_down(rs,  off, 64);
            rss += __shfl_down(rss, off, 64);
        }
        if (lane == 0) { sbuf[0] = rs; sbuf[1] = rss; }
    }
    __syncthreads();
    float2 r = make_float2(sbuf[0], sbuf[1]);
    __syncthreads();
    return r;
}

struct LNStat { float mu, rstd; };

__device__ __forceinline__ LNStat ln_stats(float4 v, float* sbuf) {
    float s  = v.x + v.y + v.z + v.w;
    float ss = v.x * v.x + v.y * v.y + v.z * v.z + v.w * v.w;
    float2 r = block_reduce2(s, ss, sbuf);
    LNStat o;
    o.mu = r.x * (1.0f / NN);
    float var = r.y * (1.0f / NN) - o.mu * o.mu;
    o.rstd = rsqrtf(var + 1e-5f);
    return o;
}

__device__ __forceinline__ float4 ln_apply(float4 v, LNStat st, float4 g, float4 b) {
    return make_float4((v.x - st.mu) * st.rstd * g.x + b.x,
                       (v.y - st.mu) * st.rstd * g.y + b.y,
                       (v.z - st.mu) * st.rstd * g.z + b.z,
                       (v.w - st.mu) * st.rstd * g.w + b.w);
}

__device__ __forceinline__ float4 relu4(float4 v) {
    return make_float4(fmaxf(v.x, 0.f), fmaxf(v.y, 0.f), fmaxf(v.z, 0.f), fmaxf(v.w, 0.f));
}

// ---------- GEMV core: 256-thread block handles 16 consecutive rows ----------
// x staged in LDS (16x reuse). Each wave computes 4 rows; inner loop issues
// 16 global_load_dwordx4 back-to-back (16KB in flight per wave) before any
// consumption -> deep MLP to cover the ~900cy HBM latency.

__device__ __forceinline__ void gemv16(const float* __restrict__ W,
                                       const float4* __restrict__ xs,  // LDS
                                       float* __restrict__ y) {
    const int wave = threadIdx.x >> 6;
    const int lane = threadIdx.x & 63;
    const int r0 = blockIdx.x * ROWS_PER_BLOCK + wave * RPW;
    const float4* __restrict__ Wr = reinterpret_cast<const float4*>(W) + (size_t)r0 * NV4;
    float acc[RPW] = {0.f, 0.f, 0.f, 0.f};
    #pragma unroll
    for (int it = 0; it < 4; ++it) {
        const int jb = (it << 8) + lane;     // float4 index within the row
        float4 w[RPW][4];
        #pragma unroll
        for (int r = 0; r < RPW; ++r) {
            #pragma unroll
            for (int k = 0; k < 4; ++k)
                w[r][k] = Wr[(size_t)r * NV4 + jb + (k << 6)];
        }
        float4 xv[4];
        #pragma unroll
        for (int k = 0; k < 4; ++k) xv[k] = xs[jb + (k << 6)];
        #pragma unroll
        for (int r = 0; r < RPW; ++r) {
            #pragma unroll
            for (int k = 0; k < 4; ++k) {
                acc[r] = fmaf(w[r][k].x, xv[k].x, acc[r]);
                acc[r] = fmaf(w[r][k].y, xv[k].y, acc[r]);
                acc[r] = fmaf(w[r][k].z, xv[k].z, acc[r]);
                acc[r] = fmaf(w[r][k].w, xv[k].w, acc[r]);
            }
        }
    }
    #pragma unroll
    for (int off = 32; off > 0; off >>= 1) {
        #pragma unroll
        for (int r = 0; r < RPW; ++r) acc[r] += __shfl_down(acc[r], off, 64);
    }
    if (lane == 0) {
        #pragma unroll
        for (int r = 0; r < RPW; ++r) y[r0 + r] = acc[r];
    }
}

// Stage A: mv1 = W_H1_H1 @ h1_prev; mv2 = W_H2_H2 @ h2_prev; mv3 = W_I_H1 @ (input_raw + b_i)
__global__ __launch_bounds__(BLK) void gemv_stageA(
    const float* __restrict__ W_H1_H1, const float* __restrict__ h1_prev,
    const float* __restrict__ W_H2_H2, const float* __restrict__ h2_prev,
    const float* __restrict__ W_I_H1,  const float* __restrict__ input_raw,
    const float* __restrict__ b_i,
    float* __restrict__ mv1, float* __restrict__ mv2, float* __restrict__ mv3)
{
    __shared__ float4 xs[NV4];
    const float* W; const float* x; const float* xadd; float* y;
    if (blockIdx.y == 0)      { W = W_H1_H1; x = h1_prev;   xadd = nullptr; y = mv1; }
    else if (blockIdx.y == 1) { W = W_H2_H2; x = h2_prev;   xadd = nullptr; y = mv2; }
    else                      { W = W_I_H1;  x = input_raw; xadd = b_i;     y = mv3; }

    const float4* x4 = reinterpret_cast<const float4*>(x);
    if (xadd) {
        const float4* a4 = reinterpret_cast<const float4*>(xadd);
        #pragma unroll
        for (int k = 0; k < 4; ++k) {
            const int j = (k << 8) + threadIdx.x;
            xs[j] = add4(x4[j], a4[j]);
        }
    } else {
        #pragma unroll
        for (int k = 0; k < 4; ++k) {
            const int j = (k << 8) + threadIdx.x;
            xs[j] = x4[j];
        }
    }
    __syncthreads();
    gemv16(W, xs, y);
}

// Pair of independent GEMVs (stages B and C)
__global__ __launch_bounds__(BLK) void gemv_pair(
    const float* __restrict__ Wa, const float* __restrict__ xa, float* __restrict__ ya,
    const float* __restrict__ Wb, const float* __restrict__ xb, float* __restrict__ yb)
{
    __shared__ float4 xs[NV4];
    const float* W; const float* x; float* y;
    if (blockIdx.y == 0) { W = Wa; x = xa; y = ya; }
    else                 { W = Wb; x = xb; y = yb; }
    const float4* x4 = reinterpret_cast<const float4*>(x);
    #pragma unroll
    for (int k = 0; k < 4; ++k) {
        const int j = (k << 8) + threadIdx.x;
        xs[j] = x4[j];
    }
    __syncthreads();
    gemv16(W, xs, y);
}

// ---------- Phase 2: two independent LN chains, one block each ----------
__global__ __launch_bounds__(1024) void phase2_kernel(
    const float* __restrict__ mv1, const float* __restrict__ mv2, const float* __restrict__ mv3,
    const float* __restrict__ bias_h1, const float* __restrict__ bias_h2,
    const float* __restrict__ g_h1, const float* __restrict__ bln_h1,
    const float* __restrict__ g_h2, const float* __restrict__ bln_h2,
    float* __restrict__ h1_p2, float* __restrict__ h2_p2)
{
    __shared__ float sbuf[32];
    const int t = threadIdx.x;
    if (blockIdx.x == 0) {
        float4 g = ld4(g_h1, t), b = ld4(bln_h1, t);
        float4 v = ld4(mv1, t);
        LNStat s1 = ln_stats(v, sbuf);
        float4 fb = ln_apply(v, s1, g, b);
        float4 tt = add4(add4(ld4(mv3, t), fb), ld4(bias_h1, t));
        LNStat s2 = ln_stats(tt, sbuf);
        st4(h1_p2, t, relu4(ln_apply(tt, s2, g, b)));
    } else {
        float4 g = ld4(g_h2, t), b = ld4(bln_h2, t);
        float4 v = ld4(mv2, t);
        LNStat s1 = ln_stats(v, sbuf);
        float4 fb = ln_apply(v, s1, g, b);
        float4 tt = add4(fb, ld4(bias_h2, t));
        LNStat s2 = ln_stats(tt, sbuf);
        st4(h2_p2, t, relu4(ln_apply(tt, s2, g, b)));
    }
}

// ---------- Phase 3 norms: two independent LNs, one block each ----------
__global__ __launch_bounds__(1024) void phase3_kernel(
    const float* __restrict__ mv4, const float* __restrict__ mv5,
    const float* __restrict__ bias_h1, const float* __restrict__ bias_h2,
    const float* __restrict__ g_h1, const float* __restrict__ bln_h1,
    const float* __restrict__ g_h2, const float* __restrict__ bln_h2,
    float* __restrict__ h1_f, float* __restrict__ h2_f)
{
    __shared__ float sbuf[32];
    const int t = threadIdx.x;
    const float* mv;  const float* bias; const float* g; const float* b; float* out;
    if (blockIdx.x == 0) { mv = mv4; bias = bias_h1; g = g_h1; b = bln_h1; out = h1_f; }
    else                 { mv = mv5; bias = bias_h2; g = g_h2; b = bln_h2; out = h2_f; }
    float4 v = add4(ld4(mv, t), ld4(bias, t));
    LNStat s = ln_stats(v, sbuf);
    st4(out, t, relu4(ln_apply(v, s, ld4(g, t), ld4(b, t))));
}

// ---------- Final: o = tanh(LN(bln_o + mv6 + mv7 + bias_o, g_o, bln_o)) ----------
__global__ __launch_bounds__(1024) void final_kernel(
    const float* __restrict__ mv6, const float* __restrict__ mv7,
    const float* __restrict__ bias_o, const float* __restrict__ bln_o,
    const float* __restrict__ g_o,
    float* __restrict__ out)
{
    __shared__ float sbuf[32];
    const int t = threadIdx.x;
    float4 v = add4(add4(ld4(bln_o, t), ld4(mv6, t)), add4(ld4(mv7, t), ld4(bias_o, t)));
    LNStat s = ln_stats(v, sbuf);
    float4 r = ln_apply(v, s, ld4(g_o, t), ld4(bln_o, t));
    st4(out, t, make_float4(tanhf(r.x), tanhf(r.y), tanhf(r.z), tanhf(r.w)));
}

// ---------- launch ----------

extern "C" void kernel_launch(void* const* d_in, const int* in_sizes, int n_in,
                              void* d_out, int out_size, void* d_ws, size_t ws_size,
                              hipStream_t stream) {
    const float* input_raw = (const float*)d_in[0];
    const float* h1_prev   = (const float*)d_in[1];
    const float* h2_prev   = (const float*)d_in[2];
    const float* W_I_H1    = (const float*)d_in[3];
    const float* W_H1_H1   = (const float*)d_in[4];
    const float* W_H1_H2   = (const float*)d_in[5];
    const float* W_H2_H1   = (const float*)d_in[6];
    const float* W_H2_H2   = (const float*)d_in[7];
    const float* W_H1_O    = (const float*)d_in[8];
    const float* W_H2_O    = (const float*)d_in[9];
    const float* bias_h1   = (const float*)d_in[10];
    const float* bias_h2   = (const float*)d_in[11];
    const float* bias_o    = (const float*)d_in[12];
    // d_in[13] = g_i (unused: LN(zeros) == beta)
    const float* b_i       = (const float*)d_in[14];
    const float* g_h1      = (const float*)d_in[15];
    const float* bln_h1    = (const float*)d_in[16];
    const float* g_h2      = (const float*)d_in[17];
    const float* bln_h2    = (const float*)d_in[18];
    const float* g_o       = (const float*)d_in[19];
    const float* bln_o     = (const float*)d_in[20];

    float* ws    = (float*)d_ws;
    float* mv1   = ws;
    float* mv2   = ws + 1 * NN;
    float* mv3   = ws + 2 * NN;
    float* h1_p2 = ws + 3 * NN;
    float* h2_p2 = ws + 4 * NN;
    float* mv4   = ws + 5 * NN;
    float* mv5   = ws + 6 * NN;
    float* h1_f  = ws + 7 * NN;
    float* h2_f  = ws + 8 * NN;
    float* mv6   = ws + 9 * NN;
    float* mv7   = ws + 10 * NN;

    const int gx = NN / ROWS_PER_BLOCK;  // 256 blocks per matrix

    // Stage A: 3 independent GEMVs
    gemv_stageA<<<dim3(gx, 3), BLK, 0, stream>>>(
        W_H1_H1, h1_prev, W_H2_H2, h2_prev, W_I_H1, input_raw, b_i, mv1, mv2, mv3);

    // Phase 2 LN chains
    phase2_kernel<<<2, 1024, 0, stream>>>(
        mv1, mv2, mv3, bias_h1, bias_h2, g_h1, bln_h1, g_h2, bln_h2, h1_p2, h2_p2);

    // Stage B: mv4 = W_H2_H1 @ h2_p2 ; mv5 = W_H1_H2 @ h1_p2
    gemv_pair<<<dim3(gx, 2), BLK, 0, stream>>>(
        W_H2_H1, h2_p2, mv4, W_H1_H2, h1_p2, mv5);

    // Phase 3 norms
    phase3_kernel<<<2, 1024, 0, stream>>>(
        mv4, mv5, bias_h1, bias_h2, g_h1, bln_h1, g_h2, bln_h2, h1_f, h2_f);

    // Stage C: mv6 = W_H1_O @ h1_f ; mv7 = W_H2_O @ h2_f
    gemv_pair<<<dim3(gx, 2), BLK, 0, stream>>>(
        W_H1_O, h1_f, mv6, W_H2_O, h2_f, mv7);

    // Final output
    final_kernel<<<1, 1024, 0, stream>>>(
        mv6, mv7, bias_o, bln_o, g_o, (float*)d_out);
}

// Round 4
// 100.146 us; speedup vs baseline: 1.1441x; 1.1441x over previous
//
#include <hip/hip_runtime.h>
#include <math.h>

#define NN 4096
#define NV4 1024            // NN/4 float4s per row
#define RPW 4               // rows per wave
#define ROWS_PER_BLOCK 16   // 4 waves x 4 rows
#define BLK 256

// ---------- small helpers ----------

__device__ __forceinline__ float4 ld4(const float* __restrict__ p, int t) {
    return reinterpret_cast<const float4*>(p)[t];
}
__device__ __forceinline__ void st4(float* __restrict__ p, int t, float4 v) {
    reinterpret_cast<float4*>(p)[t] = v;
}
__device__ __forceinline__ float4 add4(float4 a, float4 b) {
    return make_float4(a.x + b.x, a.y + b.y, a.z + b.z, a.w + b.w);
}

// block-wide (sum, sumsq) reduction, blockDim.x == 1024 (16 waves)
__device__ __forceinline__ float2 block_reduce2(float s, float ss, float* sbuf) {
    #pragma unroll
    for (int off = 32; off > 0; off >>= 1) {
        s  += __shfl_down(s,  off, 64);
        ss += __shfl_down(ss, off, 64);
    }
    const int wave = threadIdx.x >> 6;
    const int lane = threadIdx.x & 63;
    if (lane == 0) { sbuf[wave] = s; sbuf[16 + wave] = ss; }
    __syncthreads();
    float rs = 0.f, rss = 0.f;
    if (threadIdx.x < 16) { rs = sbuf[threadIdx.x]; rss = sbuf[16 + threadIdx.x]; }
    if (wave == 0) {
        #pragma unroll
        for (int off = 8; off > 0; off >>= 1) {
            rs  += __shfl_down(rs,  off, 64);
            rss += __shfl_down(rss, off, 64);
        }
        if (lane == 0) { sbuf[0] = rs; sbuf[1] = rss; }
    }
    __syncthreads();
    float2 r = make_float2(sbuf[0], sbuf[1]);
    __syncthreads();
    return r;
}

struct LNStat { float mu, rstd; };

__device__ __forceinline__ LNStat ln_stats(float4 v, float* sbuf) {
    float s  = v.x + v.y + v.z + v.w;
    float ss = v.x * v.x + v.y * v.y + v.z * v.z + v.w * v.w;
    float2 r = block_reduce2(s, ss, sbuf);
    LNStat o;
    o.mu = r.x * (1.0f / NN);
    float var = r.y * (1.0f / NN) - o.mu * o.mu;
    o.rstd = rsqrtf(var + 1e-5f);
    return o;
}

__device__ __forceinline__ float4 ln_apply(float4 v, LNStat st, float4 g, float4 b) {
    return make_float4((v.x - st.mu) * st.rstd * g.x + b.x,
                       (v.y - st.mu) * st.rstd * g.y + b.y,
                       (v.z - st.mu) * st.rstd * g.z + b.z,
                       (v.w - st.mu) * st.rstd * g.w + b.w);
}

__device__ __forceinline__ float4 relu4(float4 v) {
    return make_float4(fmaxf(v.x, 0.f), fmaxf(v.y, 0.f), fmaxf(v.z, 0.f), fmaxf(v.w, 0.f));
}

// ---------- GEMV core: 256-thread block handles 16 consecutive rows ----------
// x staged in LDS (16x reuse). Each wave computes 4 rows. Each row is read as
// 16 chunks of 1KB, processed as a ROTATED RING (start chunk = per-wave rot):
// de-synchronizes the chip-wide k-phase so instantaneous HBM traffic spreads
// across all channels instead of camping on the chunk-k channel subset.

__device__ __forceinline__ void gemv16(const float* __restrict__ W,
                                       const float4* __restrict__ xs,  // LDS
                                       float* __restrict__ y, int rotbase) {
    const int wave = threadIdx.x >> 6;
    const int lane = threadIdx.x & 63;
    const int r0 = blockIdx.x * ROWS_PER_BLOCK + wave * RPW;
    const int rot = (blockIdx.x * 4 + wave + rotbase) & 15;
    const float4* __restrict__ Wr = reinterpret_cast<const float4*>(W) + (size_t)r0 * NV4;
    float acc[RPW] = {0.f, 0.f, 0.f, 0.f};
    #pragma unroll
    for (int it = 0; it < 4; ++it) {
        int j[4];
        #pragma unroll
        for (int k = 0; k < 4; ++k) {
            const int c = (it * 4 + k + rot) & 15;   // rotated 1KB-chunk index
            j[k] = (c << 6) + lane;                  // float4 index within row
        }
        float4 w[RPW][4];
        #pragma unroll
        for (int r = 0; r < RPW; ++r) {
            #pragma unroll
            for (int k = 0; k < 4; ++k)
                w[r][k] = Wr[(size_t)r * NV4 + j[k]];
        }
        float4 xv[4];
        #pragma unroll
        for (int k = 0; k < 4; ++k) xv[k] = xs[j[k]];
        #pragma unroll
        for (int r = 0; r < RPW; ++r) {
            #pragma unroll
            for (int k = 0; k < 4; ++k) {
                acc[r] = fmaf(w[r][k].x, xv[k].x, acc[r]);
                acc[r] = fmaf(w[r][k].y, xv[k].y, acc[r]);
                acc[r] = fmaf(w[r][k].z, xv[k].z, acc[r]);
                acc[r] = fmaf(w[r][k].w, xv[k].w, acc[r]);
            }
        }
    }
    #pragma unroll
    for (int off = 32; off > 0; off >>= 1) {
        #pragma unroll
        for (int r = 0; r < RPW; ++r) acc[r] += __shfl_down(acc[r], off, 64);
    }
    if (lane == 0) {
        #pragma unroll
        for (int r = 0; r < RPW; ++r) y[r0 + r] = acc[r];
    }
}

// Stage A: mv1 = W_H1_H1 @ h1_prev; mv2 = W_H2_H2 @ h2_prev; mv3 = W_I_H1 @ (input_raw + b_i)
__global__ __launch_bounds__(BLK) void gemv_stageA(
    const float* __restrict__ W_H1_H1, const float* __restrict__ h1_prev,
    const float* __restrict__ W_H2_H2, const float* __restrict__ h2_prev,
    const float* __restrict__ W_I_H1,  const float* __restrict__ input_raw,
    const float* __restrict__ b_i,
    float* __restrict__ mv1, float* __restrict__ mv2, float* __restrict__ mv3)
{
    __shared__ float4 xs[NV4];
    const float* W; const float* x; const float* xadd; float* y;
    if (blockIdx.y == 0)      { W = W_H1_H1; x = h1_prev;   xadd = nullptr; y = mv1; }
    else if (blockIdx.y == 1) { W = W_H2_H2; x = h2_prev;   xadd = nullptr; y = mv2; }
    else                      { W = W_I_H1;  x = input_raw; xadd = b_i;     y = mv3; }

    const float4* x4 = reinterpret_cast<const float4*>(x);
    if (xadd) {
        const float4* a4 = reinterpret_cast<const float4*>(xadd);
        #pragma unroll
        for (int k = 0; k < 4; ++k) {
            const int j = (k << 8) + threadIdx.x;
            xs[j] = add4(x4[j], a4[j]);
        }
    } else {
        #pragma unroll
        for (int k = 0; k < 4; ++k) {
            const int j = (k << 8) + threadIdx.x;
            xs[j] = x4[j];
        }
    }
    __syncthreads();
    gemv16(W, xs, y, blockIdx.y * 5);
}

// Pair of independent GEMVs (stages B and C)
__global__ __launch_bounds__(BLK) void gemv_pair(
    const float* __restrict__ Wa, const float* __restrict__ xa, float* __restrict__ ya,
    const float* __restrict__ Wb, const float* __restrict__ xb, float* __restrict__ yb)
{
    __shared__ float4 xs[NV4];
    const float* W; const float* x; float* y;
    if (blockIdx.y == 0) { W = Wa; x = xa; y = ya; }
    else                 { W = Wb; x = xb; y = yb; }
    const float4* x4 = reinterpret_cast<const float4*>(x);
    #pragma unroll
    for (int k = 0; k < 4; ++k) {
        const int j = (k << 8) + threadIdx.x;
        xs[j] = x4[j];
    }
    __syncthreads();
    gemv16(W, xs, y, blockIdx.y * 7);
}

// ---------- Phase 2: two independent LN chains, one block each ----------
__global__ __launch_bounds__(1024) void phase2_kernel(
    const float* __restrict__ mv1, const float* __restrict__ mv2, const float* __restrict__ mv3,
    const float* __restrict__ bias_h1, const float* __restrict__ bias_h2,
    const float* __restrict__ g_h1, const float* __restrict__ bln_h1,
    const float* __restrict__ g_h2, const float* __restrict__ bln_h2,
    float* __restrict__ h1_p2, float* __restrict__ h2_p2)
{
    __shared__ float sbuf[32];
    const int t = threadIdx.x;
    if (blockIdx.x == 0) {
        float4 g = ld4(g_h1, t), b = ld4(bln_h1, t);
        float4 v = ld4(mv1, t);
        LNStat s1 = ln_stats(v, sbuf);
        float4 fb = ln_apply(v, s1, g, b);
        float4 tt = add4(add4(ld4(mv3, t), fb), ld4(bias_h1, t));
        LNStat s2 = ln_stats(tt, sbuf);
        st4(h1_p2, t, relu4(ln_apply(tt, s2, g, b)));
    } else {
        float4 g = ld4(g_h2, t), b = ld4(bln_h2, t);
        float4 v = ld4(mv2, t);
        LNStat s1 = ln_stats(v, sbuf);
        float4 fb = ln_apply(v, s1, g, b);
        float4 tt = add4(fb, ld4(bias_h2, t));
        LNStat s2 = ln_stats(tt, sbuf);
        st4(h2_p2, t, relu4(ln_apply(tt, s2, g, b)));
    }
}

// ---------- Phase 3 norms: two independent LNs, one block each ----------
__global__ __launch_bounds__(1024) void phase3_kernel(
    const float* __restrict__ mv4, const float* __restrict__ mv5,
    const float* __restrict__ bias_h1, const float* __restrict__ bias_h2,
    const float* __restrict__ g_h1, const float* __restrict__ bln_h1,
    const float* __restrict__ g_h2, const float* __restrict__ bln_h2,
    float* __restrict__ h1_f, float* __restrict__ h2_f)
{
    __shared__ float sbuf[32];
    const int t = threadIdx.x;
    const float* mv;  const float* bias; const float* g; const float* b; float* out;
    if (blockIdx.x == 0) { mv = mv4; bias = bias_h1; g = g_h1; b = bln_h1; out = h1_f; }
    else                 { mv = mv5; bias = bias_h2; g = g_h2; b = bln_h2; out = h2_f; }
    float4 v = add4(ld4(mv, t), ld4(bias, t));
    LNStat s = ln_stats(v, sbuf);
    st4(out, t, relu4(ln_apply(v, s, ld4(g, t), ld4(b, t))));
}

// ---------- Final: o = tanh(LN(bln_o + mv6 + mv7 + bias_o, g_o, bln_o)) ----------
__global__ __launch_bounds__(1024) void final_kernel(
    const float* __restrict__ mv6, const float* __restrict__ mv7,
    const float* __restrict__ bias_o, const float* __restrict__ bln_o,
    const float* __restrict__ g_o,
    float* __restrict__ out)
{
    __shared__ float sbuf[32];
    const int t = threadIdx.x;
    float4 v = add4(add4(ld4(bln_o, t), ld4(mv6, t)), add4(ld4(mv7, t), ld4(bias_o, t)));
    LNStat s = ln_stats(v, sbuf);
    float4 r = ln_apply(v, s, ld4(g_o, t), ld4(bln_o, t));
    st4(out, t, make_float4(tanhf(r.x), tanhf(r.y), tanhf(r.z), tanhf(r.w)));
}

// ---------- launch ----------

extern "C" void kernel_launch(void* const* d_in, const int* in_sizes, int n_in,
                              void* d_out, int out_size, void* d_ws, size_t ws_size,
                              hipStream_t stream) {
    const float* input_raw = (const float*)d_in[0];
    const float* h1_prev   = (const float*)d_in[1];
    const float* h2_prev   = (const float*)d_in[2];
    const float* W_I_H1    = (const float*)d_in[3];
    const float* W_H1_H1   = (const float*)d_in[4];
    const float* W_H1_H2   = (const float*)d_in[5];
    const float* W_H2_H1   = (const float*)d_in[6];
    const float* W_H2_H2   = (const float*)d_in[7];
    const float* W_H1_O    = (const float*)d_in[8];
    const float* W_H2_O    = (const float*)d_in[9];
    const float* bias_h1   = (const float*)d_in[10];
    const float* bias_h2   = (const float*)d_in[11];
    const float* bias_o    = (const float*)d_in[12];
    // d_in[13] = g_i (unused: LN(zeros) == beta)
    const float* b_i       = (const float*)d_in[14];
    const float* g_h1      = (const float*)d_in[15];
    const float* bln_h1    = (const float*)d_in[16];
    const float* g_h2      = (const float*)d_in[17];
    const float* bln_h2    = (const float*)d_in[18];
    const float* g_o       = (const float*)d_in[19];
    const float* bln_o     = (const float*)d_in[20];

    float* ws    = (float*)d_ws;
    float* mv1   = ws;
    float* mv2   = ws + 1 * NN;
    float* mv3   = ws + 2 * NN;
    float* h1_p2 = ws + 3 * NN;
    float* h2_p2 = ws + 4 * NN;
    float* mv4   = ws + 5 * NN;
    float* mv5   = ws + 6 * NN;
    float* h1_f  = ws + 7 * NN;
    float* h2_f  = ws + 8 * NN;
    float* mv6   = ws + 9 * NN;
    float* mv7   = ws + 10 * NN;

    const int gx = NN / ROWS_PER_BLOCK;  // 256 blocks per matrix

    // Stage A: 3 independent GEMVs
    gemv_stageA<<<dim3(gx, 3), BLK, 0, stream>>>(
        W_H1_H1, h1_prev, W_H2_H2, h2_prev, W_I_H1, input_raw, b_i, mv1, mv2, mv3);

    // Phase 2 LN chains
    phase2_kernel<<<2, 1024, 0, stream>>>(
        mv1, mv2, mv3, bias_h1, bias_h2, g_h1, bln_h1, g_h2, bln_h2, h1_p2, h2_p2);

    // Stage B: mv4 = W_H2_H1 @ h2_p2 ; mv5 = W_H1_H2 @ h1_p2
    gemv_pair<<<dim3(gx, 2), BLK, 0, stream>>>(
        W_H2_H1, h2_p2, mv4, W_H1_H2, h1_p2, mv5);

    // Phase 3 norms
    phase3_kernel<<<2, 1024, 0, stream>>>(
        mv4, mv5, bias_h1, bias_h2, g_h1, bln_h1, g_h2, bln_h2, h1_f, h2_f);

    // Stage C: mv6 = W_H1_O @ h1_f ; mv7 = W_H2_O @ h2_f
    gemv_pair<<<dim3(gx, 2), BLK, 0, stream>>>(
        W_H1_O, h1_f, mv6, W_H2_O, h2_f, mv7);

    // Final output
    final_kernel<<<1, 1024, 0, stream>>>(
        mv6, mv7, bias_o, bln_o, g_o, (float*)d_out);
}